// Round 1
// baseline (2018.974 us; speedup 1.0000x reference)
//
#include <hip/hip_runtime.h>
#include <math.h>

// Clockwork RNN, B=512 T=192 DX=32 DH1=256 DH2=512 DY=4
// Persistent-block design: block = (8 batch rows, one y); grid = 64*4 = 256
// blocks (1 per CU). h kept in LDS transposed [k][m] so broadcast float4
// reads feed 4 FMAs; w_h[y] streamed from L2 (one y per XCD by grid layout).

#define TT  192
#define DXX 32
#define DH1 256
#define DH2 512
#define NY  4
#define BB  8

__global__ __launch_bounds__(256) void cwrnn_persist(
    const float* __restrict__ x,     // [B,T,DX]
    const float* __restrict__ w_x,   // [DY,DX,DH1]
    const float* __restrict__ w_h,   // [DY,DH1,DH1]
    const float* __restrict__ bias,  // [DY,DH1]
    const float* __restrict__ W1,    // [DY,DH1,DH2]
    const float* __restrict__ b1,    // [DY,DH2]
    const float* __restrict__ W2,    // [DY,DH2]
    const float* __restrict__ b2,    // [DY]
    float* __restrict__ out)         // [B,DY]
{
    __shared__ float sh_h[DH1 * BB];    // h transposed: [k][m], 8 KB
    __shared__ float sh_wx[DXX * DH1];  // w_x[y]: [k][col], 32 KB
    __shared__ float sh_x[DXX * BB];    // x tile transposed: [k][m], 1 KB
    __shared__ float sh_b[DH1];
    __shared__ float sh_hid[DH2 * BB];  // hid transposed: [e][m], 16 KB
    __shared__ float sh_red[4][BB];

    const int t  = threadIdx.x;
    const int y  = blockIdx.x & 3;
    const int b0 = (blockIdx.x >> 2) * BB;

    const float* wx_g = w_x + (size_t)y * DXX * DH1;
    const float* wh_g = w_h + (size_t)y * DH1 * DH1;

    // Stage per-y constants; init h = 0.
    for (int i = t; i < DXX * DH1; i += 256) sh_wx[i] = wx_g[i];
    if (t < DH1) sh_b[t] = bias[y * DH1 + t];
    for (int i = t; i < DH1 * BB; i += 256) sh_h[i] = 0.f;
    __syncthreads();

    // Thread mapping: colgroup c -> output cols {2c, 2c+1}; rowhalf rh ->
    // batch rows rh*4 .. rh*4+3.  Waves are uniform in rh; NC masking is
    // wave-uniform for NC=128 and mostly uniform otherwise.
    const int c    = t & 127;
    const int rh   = t >> 7;
    const int col0 = 2 * c;

    for (int j = 0; j < TT; ++j) {
        // Stage x[:, j, :] transposed into LDS (256 elements, 256 threads).
        {
            const int k = t & 31, m = t >> 5;
            sh_x[k * BB + m] = x[(size_t)(b0 + m) * (TT * DXX) + j * DXX + k];
        }
        __syncthreads();

        const int jp = j + 1;
        int NC, NF;
        if (jp & 1)      { NC = 128; NF = 16; }   // odd step
        else if (jp & 2) { NC = 192; NF = 24; }   // even, not mult of 4
        else             { NC = 256; NF = 32; }   // mult of 4

        float a00 = 0.f, a01 = 0.f, a02 = 0.f, a03 = 0.f;
        float a10 = 0.f, a11 = 0.f, a12 = 0.f, a13 = 0.f;
        const bool active = (col0 < NC);
        if (active) {
            // Input contribution (masked features == k < NF prefix).
            for (int k = 0; k < NF; ++k) {
                const float4 xv = *(const float4*)&sh_x[k * BB + rh * 4];
                const float w0 = sh_wx[k * DH1 + col0];
                const float w1 = sh_wx[k * DH1 + col0 + 1];
                a00 += xv.x * w0; a01 += xv.y * w0; a02 += xv.z * w0; a03 += xv.w * w0;
                a10 += xv.x * w1; a11 += xv.y * w1; a12 += xv.z * w1; a13 += xv.w * w1;
            }
            // Hidden contribution: h (LDS broadcast) x w_h (L2 stream).
            #pragma unroll 4
            for (int k = 0; k < DH1; ++k) {
                const float4 hv = *(const float4*)&sh_h[k * BB + rh * 4];
                const float2 wv = *(const float2*)&wh_g[(size_t)k * DH1 + col0];
                a00 += hv.x * wv.x; a01 += hv.y * wv.x; a02 += hv.z * wv.x; a03 += hv.w * wv.x;
                a10 += hv.x * wv.y; a11 += hv.y * wv.y; a12 += hv.z * wv.y; a13 += hv.w * wv.y;
            }
        }
        __syncthreads();   // all reads of sh_h complete before update
        if (active) {
            const float bb0 = sh_b[col0], bb1 = sh_b[col0 + 1];
            float4 c0, c1;
            c0.x = tanhf(a00 + bb0); c0.y = tanhf(a01 + bb0);
            c0.z = tanhf(a02 + bb0); c0.w = tanhf(a03 + bb0);
            c1.x = tanhf(a10 + bb1); c1.y = tanhf(a11 + bb1);
            c1.z = tanhf(a12 + bb1); c1.w = tanhf(a13 + bb1);
            *(float4*)&sh_h[col0 * BB + rh * 4]       = c0;
            *(float4*)&sh_h[(col0 + 1) * BB + rh * 4] = c1;
        }
        __syncthreads();
    }

    // ---- MLP head: hid = relu(hT @ W1 + b1)  [8 x 512] ----
    // Thread t: output cols {2t, 2t+1}, all 8 rows.
    const float* W1_g = W1 + (size_t)y * DH1 * DH2;
    const int e0 = 2 * t;
    float hacc0[8], hacc1[8];
    #pragma unroll
    for (int m = 0; m < 8; ++m) { hacc0[m] = 0.f; hacc1[m] = 0.f; }
    #pragma unroll 2
    for (int k = 0; k < DH1; ++k) {
        const float2 wv = *(const float2*)&W1_g[(size_t)k * DH2 + e0];
        const float4 hA = *(const float4*)&sh_h[k * BB];
        const float4 hB = *(const float4*)&sh_h[k * BB + 4];
        hacc0[0] += hA.x * wv.x; hacc0[1] += hA.y * wv.x;
        hacc0[2] += hA.z * wv.x; hacc0[3] += hA.w * wv.x;
        hacc0[4] += hB.x * wv.x; hacc0[5] += hB.y * wv.x;
        hacc0[6] += hB.z * wv.x; hacc0[7] += hB.w * wv.x;
        hacc1[0] += hA.x * wv.y; hacc1[1] += hA.y * wv.y;
        hacc1[2] += hA.z * wv.y; hacc1[3] += hA.w * wv.y;
        hacc1[4] += hB.x * wv.y; hacc1[5] += hB.y * wv.y;
        hacc1[6] += hB.z * wv.y; hacc1[7] += hB.w * wv.y;
    }
    {
        const float bb10 = b1[y * DH2 + e0];
        const float bb11 = b1[y * DH2 + e0 + 1];
        #pragma unroll
        for (int m = 0; m < 8; ++m) {
            sh_hid[e0 * BB + m]       = fmaxf(hacc0[m] + bb10, 0.f);
            sh_hid[(e0 + 1) * BB + m] = fmaxf(hacc1[m] + bb11, 0.f);
        }
    }
    __syncthreads();

    // ---- y = hid @ W2 + b2 ----
    const float w2a = W2[y * DH2 + t];
    const float w2b = W2[y * DH2 + t + 256];
    float p[8];
    #pragma unroll
    for (int m = 0; m < 8; ++m)
        p[m] = sh_hid[t * BB + m] * w2a + sh_hid[(t + 256) * BB + m] * w2b;

    const int lane = t & 63, wid = t >> 6;
    #pragma unroll
    for (int m = 0; m < 8; ++m) {
        float v = p[m];
        for (int off = 32; off > 0; off >>= 1) v += __shfl_down(v, off);
        if (lane == 0) sh_red[wid][m] = v;
    }
    __syncthreads();
    if (t < BB) {
        out[(size_t)(b0 + t) * NY + y] =
            sh_red[0][t] + sh_red[1][t] + sh_red[2][t] + sh_red[3][t] + b2[y];
    }
}

extern "C" void kernel_launch(void* const* d_in, const int* in_sizes, int n_in,
                              void* d_out, int out_size, void* d_ws, size_t ws_size,
                              hipStream_t stream) {
    const float* x   = (const float*)d_in[0];
    const float* w_x = (const float*)d_in[1];
    const float* w_h = (const float*)d_in[2];
    const float* b   = (const float*)d_in[3];
    const float* W1  = (const float*)d_in[4];
    const float* b1  = (const float*)d_in[5];
    const float* W2  = (const float*)d_in[6];
    const float* b2  = (const float*)d_in[7];
    float* out = (float*)d_out;

    dim3 grid(256), block(256);
    hipLaunchKernelGGL(cwrnn_persist, grid, block, 0, stream,
                       x, w_x, w_h, b, W1, b1, W2, b2, out);
}

// Round 2
// 486.718 us; speedup vs baseline: 4.1481x; 4.1481x over previous
//
#include <hip/hip_runtime.h>
#include <math.h>

// Clockwork RNN, B=512 T=192 DX=32 DH1=256 DH2=512 DY=4
// R1: register-resident MFMA recurrence.
// Block = (16 batch rows, one y) -> 128 blocks. 4 waves/block, each wave owns
// 64 hidden cols and holds w_h[y][:, cols] as bf16 hi/lo MFMA A-fragments in
// VGPRs (256 VGPR). h lives in LDS as bf16 hi/lo [row][k]; per step:
//   D[col][batch] = Wt x ht via mfma_f32_16x16x32_bf16 (3-term hi/lo product)
//   + x*w_x (same scheme) + bias, tanh, packed b64 write-back.
// Clockwork masks are wave-uniform (cols) / quad-uniform (features).

#define TT   192
#define DXX  32
#define DH1  256
#define DH2  512
#define NY   4
#define ROWS 16
#define PADK 264   // padded k stride (shorts); 264*2=528B, 16B-aligned

typedef __attribute__((ext_vector_type(8))) short bf16x8;
typedef __attribute__((ext_vector_type(4))) short s16x4;
typedef __attribute__((ext_vector_type(4))) float f32x4;

__device__ __forceinline__ short f2bf(float f) {
    unsigned u = __float_as_uint(f);
    unsigned r = (u + 0x7FFFu + ((u >> 16) & 1u)) >> 16;
    return (short)r;
}
__device__ __forceinline__ float bf2f(short h) {
    return __uint_as_float(((unsigned)(unsigned short)h) << 16);
}
__device__ __forceinline__ float fast_tanh(float v) {
    // tanh(v) = 1 - 2/(exp2(v*2/ln2)+1); exp2 hw inst, rcp hw inst (~1ulp)
    float t = __builtin_amdgcn_exp2f(v * 2.885390081777927f);
    return fmaf(-2.f, __builtin_amdgcn_rcpf(t + 1.f), 1.f);
}

__global__ __launch_bounds__(256, 1) void cwrnn_mfma(
    const float* __restrict__ x,     // [B,T,DX]
    const float* __restrict__ w_x,   // [DY,DX,DH1]
    const float* __restrict__ w_h,   // [DY,DH1,DH1]
    const float* __restrict__ bias,  // [DY,DH1]
    const float* __restrict__ W1,    // [DY,DH1,DH2]
    const float* __restrict__ b1,    // [DY,DH2]
    const float* __restrict__ W2,    // [DY,DH2]
    const float* __restrict__ b2,    // [DY]
    float* __restrict__ out)         // [B,DY]
{
    __shared__ short h_hi[ROWS * PADK];     // h bf16 hi, [row][k]
    __shared__ short h_lo[ROWS * PADK];     // h bf16 lo
    __shared__ float scratch[32 * DH1];     // 32KB staging for W gathers
    __shared__ float hT[DH1 * ROWS];        // final h fp32, [k][row]
    __shared__ float red[4][ROWS];

    const int t    = threadIdx.x;
    const int lane = t & 63;
    const int w    = t >> 6;        // wave id 0..3 -> cols [64w, 64w+64)
    const int r    = lane & 15;     // frag "16-index"
    const int q    = lane >> 4;     // frag quad -> k-subrange q*8..q*8+7
    const int y    = blockIdx.x & 3;
    const int b0   = (blockIdx.x >> 2) * ROWS;
    const int colbase = w * 64;

    const float* wx_g = w_x + (size_t)y * DXX * DH1;
    const float* wh_g = w_h + (size_t)y * DH1 * DH1;

    // ---- init h = 0 ----
    for (int i = t; i < ROWS * PADK; i += 256) { h_hi[i] = 0; h_lo[i] = 0; }

    // ---- gather w_x fragments (A-operand = w_x^T tile) ----
    bf16x8 wx_hi[4], wx_lo[4];
    for (int i = t * 4; i < DXX * DH1; i += 1024)
        *(f32x4*)&scratch[i] = *(const f32x4*)&wx_g[i];
    __syncthreads();
    #pragma unroll
    for (int mt = 0; mt < 4; ++mt) {
        bf16x8 vh, vl;
        #pragma unroll
        for (int jj = 0; jj < 8; ++jj) {
            float v = scratch[(q * 8 + jj) * DH1 + colbase + mt * 16 + r];
            short hi = f2bf(v);
            vh[jj] = hi; vl[jj] = f2bf(v - bf2f(hi));
        }
        wx_hi[mt] = vh; wx_lo[mt] = vl;
    }
    __syncthreads();

    // ---- gather w_h fragments: 8 ktiles x 4 mtiles, hi/lo (256 VGPR) ----
    bf16x8 wh_hi[8][4], wh_lo[8][4];
    #pragma unroll
    for (int kt = 0; kt < 8; ++kt) {
        for (int i = t * 4; i < 32 * DH1; i += 1024)
            *(f32x4*)&scratch[i] = *(const f32x4*)&wh_g[kt * 32 * DH1 + i];
        __syncthreads();
        #pragma unroll
        for (int mt = 0; mt < 4; ++mt) {
            bf16x8 vh, vl;
            #pragma unroll
            for (int jj = 0; jj < 8; ++jj) {
                float v = scratch[(q * 8 + jj) * DH1 + colbase + mt * 16 + r];
                short hi = f2bf(v);
                vh[jj] = hi; vl[jj] = f2bf(v - bf2f(hi));
            }
            wh_hi[kt][mt] = vh; wh_lo[kt][mt] = vl;
        }
        __syncthreads();
    }

    // ---- bias fragments: lane holds bias[col] for its 4 D-rows per mtile ----
    f32x4 bias4[4];
    #pragma unroll
    for (int mt = 0; mt < 4; ++mt) {
        #pragma unroll
        for (int rr = 0; rr < 4; ++rr)
            bias4[mt][rr] = bias[y * DH1 + colbase + mt * 16 + q * 4 + rr];
    }

    // ---- recurrence ----
    for (int j = 0; j < TT; ++j) {
        const int jp = j + 1;
        int NC, NF;
        if (jp & 1)      { NC = 128; NF = 16; }
        else if (jp & 2) { NC = 192; NF = 24; }
        else             { NC = 256; NF = 32; }

        const bool act = (colbase < NC);
        f32x4 acc[4];
        f32x4 xa = {0,0,0,0}, xb = {0,0,0,0};

        if (act) {
            if (q * 8 < NF) {   // quad-uniform feature mask (NF in {16,24,32})
                const float* xp = x + ((size_t)(b0 + r) * TT + j) * DXX + q * 8;
                xa = *(const f32x4*)xp;
                xb = *(const f32x4*)(xp + 4);
            }
            #pragma unroll
            for (int mt = 0; mt < 4; ++mt) acc[mt] = bias4[mt];

            // hidden term: 8 ktiles x 4 mtiles x 3 hi/lo combos
            #pragma unroll
            for (int kt = 0; kt < 8; ++kt) {
                const bf16x8 bhi = *(const bf16x8*)&h_hi[r * PADK + kt * 32 + q * 8];
                const bf16x8 blo = *(const bf16x8*)&h_lo[r * PADK + kt * 32 + q * 8];
                #pragma unroll
                for (int mt = 0; mt < 4; ++mt) {
                    acc[mt] = __builtin_amdgcn_mfma_f32_16x16x32_bf16(wh_hi[kt][mt], bhi, acc[mt], 0, 0, 0);
                    acc[mt] = __builtin_amdgcn_mfma_f32_16x16x32_bf16(wh_lo[kt][mt], bhi, acc[mt], 0, 0, 0);
                    acc[mt] = __builtin_amdgcn_mfma_f32_16x16x32_bf16(wh_hi[kt][mt], blo, acc[mt], 0, 0, 0);
                }
            }

            // input term
            bf16x8 xhi, xlo;
            #pragma unroll
            for (int e = 0; e < 4; ++e) {
                float v = xa[e];
                short hi = f2bf(v); xhi[e] = hi; xlo[e] = f2bf(v - bf2f(hi));
            }
            #pragma unroll
            for (int e = 0; e < 4; ++e) {
                float v = xb[e];
                short hi = f2bf(v); xhi[4 + e] = hi; xlo[4 + e] = f2bf(v - bf2f(hi));
            }
            #pragma unroll
            for (int mt = 0; mt < 4; ++mt) {
                acc[mt] = __builtin_amdgcn_mfma_f32_16x16x32_bf16(wx_hi[mt], xhi, acc[mt], 0, 0, 0);
                acc[mt] = __builtin_amdgcn_mfma_f32_16x16x32_bf16(wx_hi[mt], xlo, acc[mt], 0, 0, 0);
                acc[mt] = __builtin_amdgcn_mfma_f32_16x16x32_bf16(wx_lo[mt], xhi, acc[mt], 0, 0, 0);
            }
        }
        __syncthreads();   // all h reads complete before any h writes
        if (act) {
            #pragma unroll
            for (int mt = 0; mt < 4; ++mt) {
                s16x4 ph, pl;
                #pragma unroll
                for (int rr = 0; rr < 4; ++rr) {
                    float v = fast_tanh(acc[mt][rr]);
                    short hi = f2bf(v);
                    ph[rr] = hi; pl[rr] = f2bf(v - bf2f(hi));
                }
                const int off = r * PADK + colbase + mt * 16 + q * 4;
                *(s16x4*)&h_hi[off] = ph;
                *(s16x4*)&h_lo[off] = pl;
            }
        }
        __syncthreads();
    }

    // ---- rebuild h fp32, transposed [k][row] for broadcast reads ----
    for (int i = t; i < DH1 * ROWS; i += 256) {
        const int row = i & 15, k = i >> 4;
        hT[k * ROWS + row] = bf2f(h_hi[row * PADK + k]) + bf2f(h_lo[row * PADK + k]);
    }
    __syncthreads();

    // ---- head: hid = relu(h @ W1 + b1); y = hid @ W2 + b2 ----
    const float* W1_g = W1 + (size_t)y * DH1 * DH2;
    const int e0 = 2 * t;
    float a0[16], a1[16];
    #pragma unroll
    for (int m = 0; m < 16; ++m) { a0[m] = 0.f; a1[m] = 0.f; }
    for (int k = 0; k < DH1; ++k) {
        const float2 wv = *(const float2*)&W1_g[(size_t)k * DH2 + e0];
        const f32x4* hp = (const f32x4*)&hT[k * ROWS];
        #pragma unroll
        for (int g = 0; g < 4; ++g) {
            const f32x4 hv = hp[g];
            a0[g * 4 + 0] += hv[0] * wv.x; a0[g * 4 + 1] += hv[1] * wv.x;
            a0[g * 4 + 2] += hv[2] * wv.x; a0[g * 4 + 3] += hv[3] * wv.x;
            a1[g * 4 + 0] += hv[0] * wv.y; a1[g * 4 + 1] += hv[1] * wv.y;
            a1[g * 4 + 2] += hv[2] * wv.y; a1[g * 4 + 3] += hv[3] * wv.y;
        }
    }
    {
        const float b1a = b1[y * DH2 + e0], b1b = b1[y * DH2 + e0 + 1];
        const float w2a = W2[y * DH2 + e0], w2b = W2[y * DH2 + e0 + 1];
        float p[16];
        #pragma unroll
        for (int m = 0; m < 16; ++m)
            p[m] = fmaxf(a0[m] + b1a, 0.f) * w2a + fmaxf(a1[m] + b1b, 0.f) * w2b;
        #pragma unroll
        for (int m = 0; m < 16; ++m) {
            float v = p[m];
            for (int off = 32; off > 0; off >>= 1) v += __shfl_down(v, off);
            if (lane == 0) red[w][m] = v;
        }
    }
    __syncthreads();
    if (t < ROWS) {
        out[(size_t)(b0 + t) * NY + y] =
            red[0][t] + red[1][t] + red[2][t] + red[3][t] + b2[y];
    }
}

extern "C" void kernel_launch(void* const* d_in, const int* in_sizes, int n_in,
                              void* d_out, int out_size, void* d_ws, size_t ws_size,
                              hipStream_t stream) {
    const float* x   = (const float*)d_in[0];
    const float* w_x = (const float*)d_in[1];
    const float* w_h = (const float*)d_in[2];
    const float* b   = (const float*)d_in[3];
    const float* W1  = (const float*)d_in[4];
    const float* b1  = (const float*)d_in[5];
    const float* W2  = (const float*)d_in[6];
    const float* b2  = (const float*)d_in[7];
    float* out = (float*)d_out;

    dim3 grid(128), block(256);
    hipLaunchKernelGGL(cwrnn_mfma, grid, block, 0, stream,
                       x, w_x, w_h, b, W1, b1, W2, b2, out);
}